// Round 1
// baseline (426.604 us; speedup 1.0000x reference)
//
#include <hip/hip_runtime.h>
#include <hip/hip_bf16.h>

#define N_NODESC 5000
#define N_EDGESC 8000
#define NCFG 32
#define HDIM 64
#define NF_DIM 140
#define OPE_DIM 8
#define XN_DIM 148
#define CF_DIM 24
#define PAD 68
#define SKIP_BLOCKS 1024

// ---------------- graph build ----------------
__global__ void k_deg(const int* __restrict__ ei, int* __restrict__ deg) {
    int t = blockIdx.x * blockDim.x + threadIdx.x;
    if (t >= 2 * N_EDGESC) return;
    int d;
    if (t < N_EDGESC) d = ei[2 * t + 1];
    else d = ei[2 * (t - N_EDGESC)];
    atomicAdd(&deg[d], 1);
}

__global__ void k_scan(const int* __restrict__ deg, int* __restrict__ row_ptr) {
    __shared__ int ssum[1024];
    int t = threadIdx.x;
    const int per = (N_NODESC + 1023) / 1024; // 5
    int vals[8];
    int loc = 0;
    for (int i = 0; i < per; ++i) {
        int idx = t * per + i;
        int v = (idx < N_NODESC) ? deg[idx] : 0;
        vals[i] = loc;
        loc += v;
    }
    ssum[t] = loc;
    __syncthreads();
    for (int s = 1; s < 1024; s <<= 1) {
        int v = (t >= s) ? ssum[t - s] : 0;
        __syncthreads();
        ssum[t] += v;
        __syncthreads();
    }
    int excl = ssum[t] - loc;
    for (int i = 0; i < per; ++i) {
        int idx = t * per + i;
        if (idx < N_NODESC) row_ptr[idx] = excl + vals[i];
    }
    if (t == 1023) row_ptr[N_NODESC] = ssum[1023];
}

__global__ void k_fill(const int* __restrict__ ei, const int* __restrict__ row_ptr,
                       int* __restrict__ fill, int* __restrict__ col) {
    int t = blockIdx.x * blockDim.x + threadIdx.x;
    if (t >= 2 * N_EDGESC) return;
    int s, d;
    if (t < N_EDGESC) { s = ei[2 * t]; d = ei[2 * t + 1]; }
    else { int e = t - N_EDGESC; s = ei[2 * e + 1]; d = ei[2 * e]; }
    int pos = atomicAdd(&fill[d], 1);
    col[row_ptr[d] + pos] = s;
}

// ---------------- layer-0 precompute ----------------
__global__ void k_xn(const float* __restrict__ nf, const int* __restrict__ opcode,
                     const float* __restrict__ op_emb, float* __restrict__ xn) {
    int t = blockIdx.x * blockDim.x + threadIdx.x;
    if (t >= N_NODESC * XN_DIM) return;
    int n = t / XN_DIM, f = t - n * XN_DIM;
    float v;
    if (f < NF_DIM) v = nf[n * NF_DIM + f];
    else v = op_emb[opcode[n] * OPE_DIM + (f - NF_DIM)];
    xn[t] = v;
}

__global__ void k_aggn(const float* __restrict__ xn, const int* __restrict__ row_ptr,
                       const int* __restrict__ col, float* __restrict__ aggn) {
    int t = blockIdx.x * blockDim.x + threadIdx.x;
    if (t >= N_NODESC * XN_DIM) return;
    int n = t / XN_DIM, f = t - n * XN_DIM;
    int rs = row_ptr[n], re = row_ptr[n + 1];
    float s = 0.f;
    for (int j = rs; j < re; ++j) s += xn[col[j] * XN_DIM + f];
    float inv = (re > rs) ? 1.0f / (float)(re - rs) : 0.f;
    aggn[t] = s * inv;
}

__global__ void k_En(const float* __restrict__ xn, const float* __restrict__ aggn,
                     const float* __restrict__ Ws0, const float* __restrict__ Wn0,
                     float* __restrict__ En) {
    int t = blockIdx.x * blockDim.x + threadIdx.x;
    if (t >= N_NODESC * HDIM) return;
    int n = t >> 6, k = t & 63;
    const float* x = xn + n * XN_DIM;
    const float* a = aggn + n * XN_DIM;
    float s = 0.f;
    for (int d = 0; d < XN_DIM; ++d)
        s += x[d] * Ws0[d * HDIM + k] + a[d] * Wn0[d * HDIM + k];
    En[t] = s;
}

__global__ void k_cf(const float* __restrict__ cf, const float* __restrict__ Ws0,
                     const float* __restrict__ Wn0, const float* __restrict__ b0,
                     float* __restrict__ Fc, float* __restrict__ Gc) {
    int t = threadIdx.x;
    for (int i = t; i < NCFG * HDIM; i += 256) {
        int c = i >> 6, k = i & 63;
        float f = b0[k], g = 0.f;
        for (int d = 0; d < CF_DIM; ++d) {
            float v = cf[c * CF_DIM + d];
            f += v * Ws0[(XN_DIM + d) * HDIM + k];
            g += v * Wn0[(XN_DIM + d) * HDIM + k];
        }
        Fc[i] = f;
        Gc[i] = g;
    }
}

__global__ void k_h0(const float* __restrict__ En, const float* __restrict__ Fc,
                     const float* __restrict__ Gc, const int* __restrict__ deg,
                     float* __restrict__ h0) {
    int i4 = blockIdx.x * blockDim.x + threadIdx.x;
    if (i4 >= N_NODESC * NCFG * HDIM / 4) return;
    int n = i4 >> 9;
    int rem = i4 & 511;
    int c = rem >> 4;
    int k = (rem & 15) * 4;
    float sc = (deg[n] > 0) ? 1.f : 0.f;
    float4 e = *(const float4*)&En[n * HDIM + k];
    float4 f = *(const float4*)&Fc[c * HDIM + k];
    float4 g = *(const float4*)&Gc[c * HDIM + k];
    float4 o;
    o.x = fmaxf(e.x + f.x + sc * g.x, 0.f);
    o.y = fmaxf(e.y + f.y + sc * g.y, 0.f);
    o.z = fmaxf(e.z + f.z + sc * g.z, 0.f);
    o.w = fmaxf(e.w + f.w + sc * g.w, 0.f);
    *(float4*)&h0[(size_t)i4 * 4] = o;
}

// ---------------- fused SAGE layer (h->h) ----------------
__global__ __launch_bounds__(256) void k_sage(
    const float* __restrict__ h_in, float* __restrict__ h_out,
    const float* __restrict__ Wself, const float* __restrict__ Wneigh,
    const float* __restrict__ bias,
    const int* __restrict__ row_ptr, const int* __restrict__ col) {
    __shared__ float sWs[HDIM * HDIM];
    __shared__ float sWn[HDIM * HDIM];
    __shared__ float sXs[NCFG * PAD];
    __shared__ float sXa[NCFG * PAD];
    int t = threadIdx.x;
    for (int i = 4 * t; i < HDIM * HDIM; i += 1024) {
        *(float4*)&sWs[i] = *(const float4*)&Wself[i];
        *(float4*)&sWn[i] = *(const float4*)&Wneigh[i];
    }
    int n = blockIdx.x;
    int c = t >> 3, d0 = (t & 7) * 8;
    const float* hn = h_in + (size_t)n * (NCFG * HDIM) + c * HDIM + d0;
    float4 v0 = *(const float4*)&hn[0];
    float4 v1 = *(const float4*)&hn[4];
    *(float4*)&sXs[c * PAD + d0] = v0;
    *(float4*)&sXs[c * PAD + d0 + 4] = v1;

    int rs = row_ptr[n], re = row_ptr[n + 1];
    float a[8] = {0, 0, 0, 0, 0, 0, 0, 0};
    for (int j = rs; j < re; ++j) {
        const float* hs = h_in + (size_t)col[j] * (NCFG * HDIM) + c * HDIM + d0;
        float4 u0 = *(const float4*)&hs[0];
        float4 u1 = *(const float4*)&hs[4];
        a[0] += u0.x; a[1] += u0.y; a[2] += u0.z; a[3] += u0.w;
        a[4] += u1.x; a[5] += u1.y; a[6] += u1.z; a[7] += u1.w;
    }
    float inv = (re > rs) ? 1.f / (float)(re - rs) : 0.f;
    sXa[c * PAD + d0 + 0] = a[0] * inv;
    sXa[c * PAD + d0 + 1] = a[1] * inv;
    sXa[c * PAD + d0 + 2] = a[2] * inv;
    sXa[c * PAD + d0 + 3] = a[3] * inv;
    sXa[c * PAD + d0 + 4] = a[4] * inv;
    sXa[c * PAD + d0 + 5] = a[5] * inv;
    sXa[c * PAD + d0 + 6] = a[6] * inv;
    sXa[c * PAD + d0 + 7] = a[7] * inv;
    __syncthreads();

    int k0 = d0;
    float acc[8];
#pragma unroll
    for (int j = 0; j < 8; ++j) acc[j] = bias[k0 + j];
#pragma unroll 4
    for (int d = 0; d < HDIM; ++d) {
        float xs = sXs[c * PAD + d];
        float xa = sXa[c * PAD + d];
        float4 ws0 = *(const float4*)&sWs[d * HDIM + k0];
        float4 ws1 = *(const float4*)&sWs[d * HDIM + k0 + 4];
        float4 wn0 = *(const float4*)&sWn[d * HDIM + k0];
        float4 wn1 = *(const float4*)&sWn[d * HDIM + k0 + 4];
        acc[0] += xs * ws0.x + xa * wn0.x;
        acc[1] += xs * ws0.y + xa * wn0.y;
        acc[2] += xs * ws0.z + xa * wn0.z;
        acc[3] += xs * ws0.w + xa * wn0.w;
        acc[4] += xs * ws1.x + xa * wn1.x;
        acc[5] += xs * ws1.y + xa * wn1.y;
        acc[6] += xs * ws1.z + xa * wn1.z;
        acc[7] += xs * ws1.w + xa * wn1.w;
    }
    float4 o0, o1;
    o0.x = fmaxf(acc[0], 0.f); o0.y = fmaxf(acc[1], 0.f);
    o0.z = fmaxf(acc[2], 0.f); o0.w = fmaxf(acc[3], 0.f);
    o1.x = fmaxf(acc[4], 0.f); o1.y = fmaxf(acc[5], 0.f);
    o1.z = fmaxf(acc[6], 0.f); o1.w = fmaxf(acc[7], 0.f);
    float* outp = h_out + (size_t)n * (NCFG * HDIM) + c * HDIM + k0;
    *(float4*)&outp[0] = o0;
    *(float4*)&outp[4] = o1;
}

// ---------------- skip head: sum_n relu(h @ W + b) -> per-block partials ----------------
__global__ __launch_bounds__(256) void k_skip(
    const float* __restrict__ h, const float* __restrict__ W,
    const float* __restrict__ bias, float* __restrict__ partials) {
    __shared__ float sW[HDIM * HDIM];
    __shared__ float sX[NCFG * PAD];
    int t = threadIdx.x;
    for (int i = 4 * t; i < HDIM * HDIM; i += 1024)
        *(float4*)&sW[i] = *(const float4*)&W[i];
    int c = t >> 3, q = t & 7;
    int d0 = q * 8, k0 = q * 8;
    float bk[8];
#pragma unroll
    for (int j = 0; j < 8; ++j) bk[j] = bias[k0 + j];
    float acc[8] = {0, 0, 0, 0, 0, 0, 0, 0};
    for (int n = blockIdx.x; n < N_NODESC; n += gridDim.x) {
        __syncthreads();
        const float* hn = h + (size_t)n * (NCFG * HDIM) + c * HDIM + d0;
        *(float4*)&sX[c * PAD + d0] = *(const float4*)&hn[0];
        *(float4*)&sX[c * PAD + d0 + 4] = *(const float4*)&hn[4];
        __syncthreads();
        float s[8];
#pragma unroll
        for (int j = 0; j < 8; ++j) s[j] = bk[j];
#pragma unroll 4
        for (int d = 0; d < HDIM; ++d) {
            float x = sX[c * PAD + d];
            float4 w0 = *(const float4*)&sW[d * HDIM + k0];
            float4 w1 = *(const float4*)&sW[d * HDIM + k0 + 4];
            s[0] += x * w0.x; s[1] += x * w0.y; s[2] += x * w0.z; s[3] += x * w0.w;
            s[4] += x * w1.x; s[5] += x * w1.y; s[6] += x * w1.z; s[7] += x * w1.w;
        }
#pragma unroll
        for (int j = 0; j < 8; ++j) acc[j] += fmaxf(s[j], 0.f);
    }
    float* p = partials + (size_t)blockIdx.x * (NCFG * HDIM) + c * HDIM + k0;
    float4 o0, o1;
    o0.x = acc[0]; o0.y = acc[1]; o0.z = acc[2]; o0.w = acc[3];
    o1.x = acc[4]; o1.y = acc[5]; o1.z = acc[6]; o1.w = acc[7];
    *(float4*)&p[0] = o0;
    *(float4*)&p[4] = o1;
}

__global__ void k_reduce(const float* __restrict__ partials, float* __restrict__ S,
                         int lcol) {
    int i = blockIdx.x * blockDim.x + threadIdx.x;
    if (i >= NCFG * HDIM) return;
    float s = 0.f;
    for (int b = 0; b < SKIP_BLOCKS; ++b) s += partials[(size_t)b * (NCFG * HDIM) + i];
    int c = i >> 6, k = i & 63;
    S[c * (3 * HDIM) + lcol * HDIM + k] = s;
}

// ---------------- final MLP ----------------
__global__ void k_mlp(const float* __restrict__ S,
                      const float* __restrict__ p1w, const float* __restrict__ p1b,
                      const float* __restrict__ p2w, const float* __restrict__ p2b,
                      const float* __restrict__ p3w, const float* __restrict__ p3b,
                      float* __restrict__ out) {
    int c = blockIdx.x;
    int t = threadIdx.x;
    __shared__ float sx[192];
    __shared__ float h1[128];
    __shared__ float h2[64];
    if (t < 192) sx[t] = S[c * 192 + t];
    __syncthreads();
    if (t < 128) {
        float s = p1b[t];
        for (int d = 0; d < 192; ++d) s += sx[d] * p1w[d * 128 + t];
        h1[t] = fmaxf(s, 0.f);
    }
    __syncthreads();
    if (t < 64) {
        float s = p2b[t];
        for (int d = 0; d < 128; ++d) s += h1[d] * p2w[d * 64 + t];
        h2[t] = fmaxf(s, 0.f);
    }
    __syncthreads();
    if (t == 0) {
        float s = p3b[0];
        for (int d = 0; d < 64; ++d) s += h2[d] * p3w[d];
        out[c] = s;
    }
}

extern "C" void kernel_launch(void* const* d_in, const int* in_sizes, int n_in,
                              void* d_out, int out_size, void* d_ws, size_t ws_size,
                              hipStream_t stream) {
    const float* nf  = (const float*)d_in[0];
    const int*   opc = (const int*)d_in[1];
    const int*   ei  = (const int*)d_in[2];
    const float* cf  = (const float*)d_in[3];
    const float* ope = (const float*)d_in[4];
    const float* ws0 = (const float*)d_in[5];
    const float* wn0 = (const float*)d_in[6];
    const float* b0  = (const float*)d_in[7];
    const float* wsl = (const float*)d_in[8];
    const float* wnl = (const float*)d_in[9];
    const float* bl  = (const float*)d_in[10];
    const float* skw = (const float*)d_in[11];
    const float* skb = (const float*)d_in[12];
    const float* p1w = (const float*)d_in[13];
    const float* p1b = (const float*)d_in[14];
    const float* p2w = (const float*)d_in[15];
    const float* p2b = (const float*)d_in[16];
    const float* p3w = (const float*)d_in[17];
    const float* p3b = (const float*)d_in[18];
    float* out = (float*)d_out;

    char* w = (char*)d_ws;
    auto alloc = [&](size_t bytes) {
        char* p = w;
        w += (bytes + 255) & ~(size_t)255;
        return p;
    };
    int* deg      = (int*)alloc(N_NODESC * 4);
    int* row_ptr  = (int*)alloc((N_NODESC + 1) * 4);
    int* fill     = (int*)alloc(N_NODESC * 4);
    int* col      = (int*)alloc(2 * N_EDGESC * 4);
    float* xn     = (float*)alloc((size_t)N_NODESC * XN_DIM * 4);
    float* aggn   = (float*)alloc((size_t)N_NODESC * XN_DIM * 4);
    float* En     = (float*)alloc((size_t)N_NODESC * HDIM * 4);
    float* Fc     = (float*)alloc(NCFG * HDIM * 4);
    float* Gc     = (float*)alloc(NCFG * HDIM * 4);
    float* S      = (float*)alloc(NCFG * 3 * HDIM * 4);
    float* parts  = (float*)alloc((size_t)SKIP_BLOCKS * NCFG * HDIM * 4);
    float* h0     = (float*)alloc((size_t)N_NODESC * NCFG * HDIM * 4);
    float* h1     = (float*)alloc((size_t)N_NODESC * NCFG * HDIM * 4);

    hipMemsetAsync(deg, 0, N_NODESC * 4, stream);
    hipMemsetAsync(fill, 0, N_NODESC * 4, stream);
    k_deg<<<(2 * N_EDGESC + 255) / 256, 256, 0, stream>>>(ei, deg);
    k_scan<<<1, 1024, 0, stream>>>(deg, row_ptr);
    k_fill<<<(2 * N_EDGESC + 255) / 256, 256, 0, stream>>>(ei, row_ptr, fill, col);
    k_xn<<<(N_NODESC * XN_DIM + 255) / 256, 256, 0, stream>>>(nf, opc, ope, xn);
    k_aggn<<<(N_NODESC * XN_DIM + 255) / 256, 256, 0, stream>>>(xn, row_ptr, col, aggn);
    k_En<<<(N_NODESC * HDIM + 255) / 256, 256, 0, stream>>>(xn, aggn, ws0, wn0, En);
    k_cf<<<1, 256, 0, stream>>>(cf, ws0, wn0, b0, Fc, Gc);
    k_h0<<<(N_NODESC * NCFG * HDIM / 4 + 255) / 256, 256, 0, stream>>>(En, Fc, Gc, deg, h0);

    k_skip<<<SKIP_BLOCKS, 256, 0, stream>>>(h0, skw + 0 * 4096, skb + 0 * 64, parts);
    k_reduce<<<8, 256, 0, stream>>>(parts, S, 0);
    k_sage<<<N_NODESC, 256, 0, stream>>>(h0, h1, wsl + 0 * 4096, wnl + 0 * 4096,
                                         bl + 0 * 64, row_ptr, col);
    k_skip<<<SKIP_BLOCKS, 256, 0, stream>>>(h1, skw + 1 * 4096, skb + 1 * 64, parts);
    k_reduce<<<8, 256, 0, stream>>>(parts, S, 1);
    k_sage<<<N_NODESC, 256, 0, stream>>>(h1, h0, wsl + 1 * 4096, wnl + 1 * 4096,
                                         bl + 1 * 64, row_ptr, col);
    k_skip<<<SKIP_BLOCKS, 256, 0, stream>>>(h0, skw + 2 * 4096, skb + 2 * 64, parts);
    k_reduce<<<8, 256, 0, stream>>>(parts, S, 2);
    k_mlp<<<NCFG, 256, 0, stream>>>(S, p1w, p1b, p2w, p2b, p3w, p3b, out);
}